// Round 1
// baseline (3688.433 us; speedup 1.0000x reference)
//
#include <hip/hip_runtime.h>
#include <cstdint>

#define LH   50
#define PP   30
#define NAG  2048
#define EMBD 64
#define NHID 128
#define EHID 256
#define ADIM 64
#define CNND 2048

enum : int {
  WS_H0  = 0,
  WS_H1  = WS_H0 + EHID*NAG,
  WS_C   = WS_H1 + EHID*NAG,
  WS_WFN = WS_C  + EHID*NAG,   // 2*1024  fused (W_nemb@Wih_n)
  WS_BFN = WS_WFN + 2*1024,    // 1024    fused bias
  WS_WFT = WS_BFN + 1024,      // 2*512   fused (W_temb@Wih_t)
  WS_BFT = WS_WFT + 2*512,     // 512
  WS_TH  = WS_BFT + 512,       // 128
  WS_TC  = WS_TH + NHID,       // 128
  WS_HT  = WS_TC + NHID,       // 256
  WS_W49 = WS_HT + EHID,       // 2048 softmax weights at t=49
  WS_CN  = WS_W49 + NAG,       // 1  currN(49)
  WS_POS = WS_CN + 1,          // 2
  WS_UA  = WS_POS + 2,         // 3  (u0,u1,A)
  WS_END = WS_UA + 3
};

__device__ __forceinline__ float sigf(float x){ return 1.0f/(1.0f + __expf(-x)); }
__device__ __forceinline__ float tanhfast(float x){
  x = fminf(15.0f, fmaxf(-15.0f, x));
  float e = __expf(2.0f*x);
  return (e - 1.0f)/(e + 1.0f);
}

// ---- one-time: fold embeddings into gate weights ----------------------------
__global__ void k_setup(const float* __restrict__ Wnemb, const float* __restrict__ bnemb,
                        const float* __restrict__ Wihn,  const float* __restrict__ bihn,
                        const float* __restrict__ bhhn,
                        const float* __restrict__ Wtemb, const float* __restrict__ btemb,
                        const float* __restrict__ Wiht,  const float* __restrict__ biht,
                        const float* __restrict__ bhht,
                        float* __restrict__ ws)
{
  const int j = threadIdx.x;  // 1024
  {
    float a0=0.f, a1=0.f, ab=0.f;
    for (int k=0;k<EMBD;k++){
      const float w = Wihn[k*1024 + j];
      a0 += Wnemb[k]*w; a1 += Wnemb[EMBD+k]*w; ab += bnemb[k]*w;
    }
    ws[WS_WFN + j]        = a0;
    ws[WS_WFN + 1024 + j] = a1;
    ws[WS_BFN + j]        = ab + bihn[j] + bhhn[j];
  }
  if (j < 512){
    float a0=0.f, a1=0.f, ab=0.f;
    for (int k=0;k<EMBD;k++){
      const float w = Wiht[k*512 + j];
      a0 += Wtemb[k]*w; a1 += Wtemb[EMBD+k]*w; ab += btemb[k]*w;
    }
    ws[WS_WFT + j]       = a0;
    ws[WS_WFT + 512 + j] = a1;
    ws[WS_BFT + j]       = ab + biht[j] + bhht[j];
  }
}

// ---- init H/C (transposed [e][n]) and pos -----------------------------------
__global__ void k_init(const float* __restrict__ nh0, const float* __restrict__ nc0,
                       const float* __restrict__ tpos, float* __restrict__ ws)
{
  const int idx = blockIdx.x*256 + threadIdx.x;   // 2048 blocks -> 524288
  const int e = idx >> 11;
  ws[WS_H0 + idx] = nh0[e];
  ws[WS_C  + idx] = nc0[e];
  if (idx == 0){ ws[WS_POS] = tpos[(LH-1)*2]; ws[WS_POS+1] = tpos[(LH-1)*2+1]; }
}

// ---- precompute obs-phase softmax weights at t = L-1 ------------------------
__global__ void k_att_pre(const float* __restrict__ tpos, const float* __restrict__ trel,
                          const float* __restrict__ npos, const int* __restrict__ nhist,
                          const float* __restrict__ Wtatt, const float* __restrict__ btatt,
                          const float* __restrict__ Wnatt, const float* __restrict__ bnatt,
                          float* __restrict__ ws)
{
  __shared__ float at[ADIM];
  __shared__ float red[256];
  __shared__ float uv[3];
  const int tid = threadIdx.x;   // 256
  const int t = LH - 1;
  const float tr0 = trel[2*t], tr1 = trel[2*t+1];
  const float tp0 = tpos[2*t], tp1 = tpos[2*t+1];
  if (tid < ADIM) at[tid] = tr0*Wtatt[tid] + tr1*Wtatt[ADIM+tid] + btatt[tid];
  int cnt = 0;
  for (int n = tid; n < NAG; n += 256) cnt += (nhist[n] > (LH - t)) ? 1 : 0;
  red[tid] = (float)cnt;
  __syncthreads();
  if (tid == 0){
    float u0=0.f,u1=0.f,v=0.f;
    for (int k=0;k<ADIM;k++){ u0 += Wnatt[k]*at[k]; u1 += Wnatt[ADIM+k]*at[k]; v += bnatt[k]*at[k]; }
    uv[0]=u0; uv[1]=u1; uv[2]=v;
  }
  for (int s=128; s>0; s>>=1){ if (tid < s) red[tid] += red[tid+s]; __syncthreads(); }
  const float currN = red[0];
  __syncthreads();
  const float u0 = uv[0], u1 = uv[1], v = uv[2];
  const float scale = currN * 0.125f;
  float sc[8]; float smax = -3.0e38f;
  #pragma unroll
  for (int i=0;i<8;i++){
    const int n = tid + 256*i;
    const float p0 = npos[n*(LH*2) + 2*t], p1 = npos[n*(LH*2) + 2*t + 1];
    float s = scale * ((tp0-p0)*u0 + (tp1-p1)*u1 + v);
    s = (nhist[n] > (LH - t)) ? s : -1.0e30f;
    sc[i] = s; smax = fmaxf(smax, s);
  }
  red[tid] = smax; __syncthreads();
  for (int s=128; s>0; s>>=1){ if (tid<s) red[tid] = fmaxf(red[tid], red[tid+s]); __syncthreads(); }
  smax = red[0]; __syncthreads();
  float ssum = 0.f;
  #pragma unroll
  for (int i=0;i<8;i++){ sc[i] = __expf(sc[i]-smax); ssum += sc[i]; }
  red[tid] = ssum; __syncthreads();
  for (int s=128; s>0; s>>=1){ if (tid<s) red[tid] += red[tid+s]; __syncthreads(); }
  const float inv = 1.0f / red[0];
  #pragma unroll
  for (int i=0;i<8;i++) ws[WS_W49 + tid + 256*i] = sc[i]*inv;
  if (tid == 0) ws[WS_CN] = currN;
}

// ---- entire obs-phase target LSTM (independent chain), single block ---------
__global__ void k_target_obs(const float* __restrict__ trel, const int* __restrict__ thsp,
                             const float* __restrict__ Whht,
                             const float* __restrict__ th0, const float* __restrict__ tc0,
                             float* __restrict__ ws)
{
  __shared__ float h[NHID], c[NHID], g[4*NHID];
  const int tid = threadIdx.x;   // 512
  const int ths = thsp[0];
  if (tid < NHID){ h[tid] = th0[tid]; c[tid] = tc0[tid]; }
  __syncthreads();
  for (int t = 1; t < LH; ++t){
    const float r0 = trel[2*t], r1 = trel[2*t+1];
    float acc = r0*ws[WS_WFT+tid] + r1*ws[WS_WFT+512+tid] + ws[WS_BFT+tid];
    for (int k = 0; k < NHID; ++k) acc += h[k]*Whht[k*(4*NHID)+tid];
    g[tid] = acc;
    __syncthreads();
    if (tid < NHID && ths > LH - t){
      const float ig = sigf(g[tid]),          fg = sigf(g[NHID+tid]);
      const float gg = tanhfast(g[2*NHID+tid]), og = sigf(g[3*NHID+tid]);
      const float c2 = fg*c[tid] + ig*gg;
      c[tid] = c2; h[tid] = og*tanhfast(c2);
    }
    __syncthreads();
  }
  if (tid < NHID){ ws[WS_TH+tid] = h[tid]; ws[WS_TC+tid] = c[tid]; }
}

// ---- one nearby-LSTM step: (2048x256)@(256x1024) + gates + masked update ----
// H layout transposed: H[e][n]. Block: 32 agents x 32 hidden units (x4 gates).
__launch_bounds__(256, 2)
__global__ void k_nearby(const float* __restrict__ Hin, float* __restrict__ Hout,
                         float* __restrict__ Cst, const float* __restrict__ Whh,
                         const float* __restrict__ wfn, const float* __restrict__ bfn,
                         const float* __restrict__ rel2, const int* __restrict__ nhist,
                         int thr)
{
  __shared__ float gsh[32*129];
  const int tid = threadIdx.x;
  const int tx = tid & 31, ty = tid >> 5;
  const int m0 = blockIdx.x << 5;      // 64 blocks
  const int e0 = blockIdx.y << 5;      // 8 blocks
  const int q  = tx >> 3;
  const int ee = (tx & 7) << 2;
  const int mb = m0 + (ty << 2);
  const float* hp = Hin + mb;
  const float* wp = Whh + q*256 + e0 + ee;
  float acc[4][4];
  #pragma unroll
  for (int j=0;j<4;j++){ acc[j][0]=0.f; acc[j][1]=0.f; acc[j][2]=0.f; acc[j][3]=0.f; }

  #pragma unroll 4
  for (int k = 0; k < EHID; ++k){
    const float4 h4 = *reinterpret_cast<const float4*>(hp); 
    const float4 w4 = *reinterpret_cast<const float4*>(wp);
    hp += NAG; wp += 1024;
    acc[0][0] += h4.x*w4.x; acc[0][1] += h4.x*w4.y; acc[0][2] += h4.x*w4.z; acc[0][3] += h4.x*w4.w;
    acc[1][0] += h4.y*w4.x; acc[1][1] += h4.y*w4.y; acc[1][2] += h4.y*w4.z; acc[1][3] += h4.y*w4.w;
    acc[2][0] += h4.z*w4.x; acc[2][1] += h4.z*w4.y; acc[2][2] += h4.z*w4.z; acc[2][3] += h4.z*w4.w;
    acc[3][0] += h4.w*w4.x; acc[3][1] += h4.w*w4.y; acc[3][2] += h4.w*w4.z; acc[3][3] += h4.w*w4.w;
  }
  // rank-2 (folded embedding) + bias, then stage gates to LDS
  const int gc = q*256 + e0 + ee;
  const float4 f0 = *reinterpret_cast<const float4*>(wfn + gc);
  const float4 f1 = *reinterpret_cast<const float4*>(wfn + 1024 + gc);
  const float4 bb = *reinterpret_cast<const float4*>(bfn + gc);
  #pragma unroll
  for (int j=0;j<4;j++){
    const int m = mb + j;
    const float r0 = rel2[m*(LH*2)];
    const float r1 = rel2[m*(LH*2)+1];
    float* gr = gsh + (ty*4 + j)*129 + 4*tx;
    gr[0] = acc[j][0] + r0*f0.x + r1*f1.x + bb.x;
    gr[1] = acc[j][1] + r0*f0.y + r1*f1.y + bb.y;
    gr[2] = acc[j][2] + r0*f0.z + r1*f1.z + bb.z;
    gr[3] = acc[j][3] + r0*f0.w + r1*f1.w + bb.w;
  }
  __syncthreads();
  // phase 2: gate nonlinearities + masked h/c update, coalesced float4 writes
  const int mg = tid & 7, el = tid >> 3;
  const int mloc = mg << 2;
  const int eg = e0 + el;
  const int rowoff = eg*NAG + m0 + mloc;
  const float4 hold = *reinterpret_cast<const float4*>(Hin + rowoff);
  const float4 cold = *reinterpret_cast<const float4*>(Cst + rowoff);
  const float ho[4] = {hold.x,hold.y,hold.z,hold.w};
  const float co[4] = {cold.x,cold.y,cold.z,cold.w};
  float hn[4], cn[4];
  #pragma unroll
  for (int j=0;j<4;j++){
    const float* grr = gsh + (mloc+j)*129 + el;
    const float gi = grr[0], gf = grr[32], gg = grr[64], go = grr[96];
    const bool msk = nhist[m0 + mloc + j] > thr;
    const float ig = sigf(gi), fg = sigf(gf), g2 = tanhfast(gg), og = sigf(go);
    const float c2 = fg*co[j] + ig*g2;
    const float h2 = og*tanhfast(c2);
    cn[j] = msk ? c2 : co[j];
    hn[j] = msk ? h2 : ho[j];
  }
  *reinterpret_cast<float4*>(Hout + rowoff) = make_float4(hn[0],hn[1],hn[2],hn[3]);
  *reinterpret_cast<float4*>(Cst  + rowoff) = make_float4(cn[0],cn[1],cn[2],cn[3]);
}

// ---- final obs attention: Ht = w49 @ H  (or h0 fallback) --------------------
__global__ void k_att_obs(const float* __restrict__ Hcur, const float* __restrict__ nh0,
                          float* __restrict__ ws)
{
  const int tid = threadIdx.x;            // 1024
  const int lane = tid & 63, wave = tid >> 6;
  const float currN = ws[WS_CN];
  if (currN >= 1.0f){
    for (int e = wave; e < EHID; e += 16){
      const float* hrow = Hcur + e*NAG;
      float acc = 0.f;
      for (int n = lane*4; n < NAG; n += 256){
        const float4 h4 = *reinterpret_cast<const float4*>(hrow + n);
        const float4 w4 = *reinterpret_cast<const float4*>(ws + WS_W49 + n);
        acc += h4.x*w4.x + h4.y*w4.y + h4.z*w4.z + h4.w*w4.w;
      }
      for (int off = 32; off > 0; off >>= 1) acc += __shfl_down(acc, off);
      if (lane == 0) ws[WS_HT + e] = acc;
    }
  } else {
    if (tid < EHID) ws[WS_HT + tid] = nh0[tid];
  }
}

// ---- pred-phase fused: [attention(prev step)] -> pred -> pos -> tLSTM -> u,A
__global__ void k_attpred(const float* __restrict__ Hcur, int sidx, int do_att,
                          const float* __restrict__ img, const float* __restrict__ npos,
                          const float* __restrict__ Wpred, const float* __restrict__ bpred,
                          const float* __restrict__ Wtatt, const float* __restrict__ btatt,
                          const float* __restrict__ Wnatt, const float* __restrict__ bnatt,
                          const float* __restrict__ Whht,
                          float* __restrict__ ws, float* __restrict__ out)
{
  __shared__ float wsm[NAG];
  __shared__ float red[1024];
  __shared__ float ht[EHID];
  __shared__ float at[ADIM];
  __shared__ float gl[4*NHID];
  __shared__ float thl[NHID], tcl[NHID];
  __shared__ float pv[4];
  const int tid = threadIdx.x;      // 1024
  const int lane = tid & 63, wave = tid >> 6;

  if (do_att){
    const float u0 = ws[WS_UA], u1 = ws[WS_UA+1], A = ws[WS_UA+2];
    float sc0, sc1;
    {
      int n = tid;
      float p0 = npos[n*(LH*2) + (LH-1)*2], p1 = npos[n*(LH*2) + (LH-1)*2 + 1];
      sc0 = 256.0f * (A - (p0*u0 + p1*u1));
      n = tid + 1024;
      p0 = npos[n*(LH*2) + (LH-1)*2]; p1 = npos[n*(LH*2) + (LH-1)*2 + 1];
      sc1 = 256.0f * (A - (p0*u0 + p1*u1));
    }
    red[tid] = fmaxf(sc0, sc1);
    __syncthreads();
    for (int s = 512; s > 0; s >>= 1){ if (tid < s) red[tid] = fmaxf(red[tid], red[tid+s]); __syncthreads(); }
    const float smax = red[0];
    __syncthreads();
    const float ex0 = __expf(sc0 - smax), ex1 = __expf(sc1 - smax);
    wsm[tid] = ex0; wsm[tid+1024] = ex1;
    red[tid] = ex0 + ex1;
    __syncthreads();
    for (int s = 512; s > 0; s >>= 1){ if (tid < s) red[tid] += red[tid+s]; __syncthreads(); }
    const float inv = 1.0f / red[0];
    for (int e = wave; e < EHID; e += 16){
      const float* hrow = Hcur + e*NAG;
      float acc = 0.f;
      for (int n = lane*4; n < NAG; n += 256){
        const float4 h4 = *reinterpret_cast<const float4*>(hrow + n);
        const float4 w4 = *reinterpret_cast<const float4*>(&wsm[n]);
        acc += h4.x*w4.x + h4.y*w4.y + h4.z*w4.z + h4.w*w4.w;
      }
      for (int off = 32; off > 0; off >>= 1) acc += __shfl_down(acc, off);
      if (lane == 0){ const float v = acc * inv; ht[e] = v; ws[WS_HT + e] = v; }
    }
  } else {
    if (tid < EHID) ht[tid] = ws[WS_HT + tid];
  }
  if (tid < NHID){ thl[tid] = ws[WS_TH + tid]; tcl[tid] = ws[WS_TC + tid]; }
  __syncthreads();
  // pred head
  float a0 = 0.f, a1 = 0.f;
  for (int k = tid; k < NHID+CNND+EHID; k += 1024){
    const float v = (k < NHID) ? thl[k] : ((k < NHID+CNND) ? img[k-NHID] : ht[k-NHID-CNND]);
    a0 += v * Wpred[2*k];
    a1 += v * Wpred[2*k+1];
  }
  float2* r2 = reinterpret_cast<float2*>(wsm);
  r2[tid] = make_float2(a0, a1);
  __syncthreads();
  for (int s = 512; s > 0; s >>= 1){
    if (tid < s){ float2 b = r2[tid+s]; float2 a = r2[tid]; a.x += b.x; a.y += b.y; r2[tid] = a; }
    __syncthreads();
  }
  if (tid == 0){
    const float p0 = r2[0].x + bpred[0], p1 = r2[0].y + bpred[1];
    out[2*sidx] = p0; out[2*sidx+1] = p1;
    const float q0 = ws[WS_POS] + p0, q1 = ws[WS_POS+1] + p1;
    ws[WS_POS] = q0; ws[WS_POS+1] = q1;
    pv[0]=p0; pv[1]=p1; pv[2]=q0; pv[3]=q1;
  }
  __syncthreads();
  if (tid < ADIM) at[tid] = pv[0]*Wtatt[tid] + pv[1]*Wtatt[ADIM+tid] + btatt[tid];
  __syncthreads();
  if (tid == 0){
    float u0=0.f,u1=0.f,v=0.f;
    for (int k=0;k<ADIM;k++){ u0 += Wnatt[k]*at[k]; u1 += Wnatt[ADIM+k]*at[k]; v += bnatt[k]*at[k]; }
    ws[WS_UA] = u0; ws[WS_UA+1] = u1; ws[WS_UA+2] = pv[2]*u0 + pv[3]*u1 + v;
  }
  if (tid < 4*NHID){
    float g = pv[0]*ws[WS_WFT+tid] + pv[1]*ws[WS_WFT+512+tid] + ws[WS_BFT+tid];
    for (int k = 0; k < NHID; ++k) g += thl[k]*Whht[k*(4*NHID)+tid];
    gl[tid] = g;
  }
  __syncthreads();
  if (tid < NHID){
    const float ig = sigf(gl[tid]),            fg = sigf(gl[NHID+tid]);
    const float gg = tanhfast(gl[2*NHID+tid]), og = sigf(gl[3*NHID+tid]);
    const float c2 = fg*tcl[tid] + ig*gg;
    ws[WS_TC+tid] = c2;
    ws[WS_TH+tid] = og*tanhfast(c2);
  }
}

extern "C" void kernel_launch(void* const* d_in, const int* in_sizes, int n_in,
                              void* d_out, int out_size, void* d_ws, size_t ws_size,
                              hipStream_t stream) {
  const float* img   = (const float*)d_in[0];
  const float* tpos  = (const float*)d_in[1];
  const float* trel  = (const float*)d_in[2];
  const float* npos  = (const float*)d_in[3];
  const float* nrel  = (const float*)d_in[4];
  const int*   nhist = (const int*)d_in[5];
  const int*   ths   = (const int*)d_in[6];
  const float* th0   = (const float*)d_in[7];
  const float* tc0   = (const float*)d_in[8];
  const float* Wtemb = (const float*)d_in[9];
  const float* btemb = (const float*)d_in[10];
  const float* Wiht  = (const float*)d_in[11];
  const float* Whht  = (const float*)d_in[12];
  const float* biht  = (const float*)d_in[13];
  const float* bhht  = (const float*)d_in[14];
  const float* Wtatt = (const float*)d_in[15];
  const float* btatt = (const float*)d_in[16];
  const float* nh0   = (const float*)d_in[17];
  const float* nc0   = (const float*)d_in[18];
  const float* Wnemb = (const float*)d_in[19];
  const float* bnemb = (const float*)d_in[20];
  const float* Wihn  = (const float*)d_in[21];
  const float* Whhn  = (const float*)d_in[22];
  const float* bihn  = (const float*)d_in[23];
  const float* bhhn  = (const float*)d_in[24];
  const float* Wnatt = (const float*)d_in[25];
  const float* bnatt = (const float*)d_in[26];
  const float* Wpred = (const float*)d_in[27];
  const float* bpred = (const float*)d_in[28];
  float* ws  = (float*)d_ws;
  float* out = (float*)d_out;

  k_setup<<<1, 1024, 0, stream>>>(Wnemb, bnemb, Wihn, bihn, bhhn,
                                  Wtemb, btemb, Wiht, biht, bhht, ws);
  k_init<<<2048, 256, 0, stream>>>(nh0, nc0, tpos, ws);
  k_att_pre<<<1, 256, 0, stream>>>(tpos, trel, npos, nhist, Wtatt, btatt, Wnatt, bnatt, ws);
  k_target_obs<<<1, 512, 0, stream>>>(trel, ths, Whht, th0, tc0, ws);

  float* Hb[2] = { ws + WS_H0, ws + WS_H1 };
  for (int t = 1; t < LH; ++t){
    k_nearby<<<dim3(64,8), 256, 0, stream>>>(Hb[(t-1)&1], Hb[t&1], ws + WS_C, Whhn,
                                             ws + WS_WFN, ws + WS_BFN,
                                             nrel + 2*t, nhist, LH - t);
  }
  k_att_obs<<<1, 1024, 0, stream>>>(Hb[(LH-1)&1], nh0, ws);

  k_attpred<<<1, 1024, 0, stream>>>(Hb[(LH-1)&1], 0, 0, img, npos,
                                    Wpred, bpred, Wtatt, btatt, Wnatt, bnatt, Whht, ws, out);
  for (int s = 0; s < PP-1; ++s){
    k_nearby<<<dim3(64,8), 256, 0, stream>>>(Hb[(LH-1+s)&1], Hb[(LH+s)&1], ws + WS_C, Whhn,
                                             ws + WS_WFN, ws + WS_BFN,
                                             nrel + 2*(LH-1), nhist, -1);
    k_attpred<<<1, 1024, 0, stream>>>(Hb[(LH+s)&1], s+1, 1, img, npos,
                                      Wpred, bpred, Wtatt, btatt, Wnatt, bnatt, Whht, ws, out);
  }
}

// Round 3
// 1761.430 us; speedup vs baseline: 2.0940x; 2.0940x over previous
//
#include <hip/hip_runtime.h>
#include <hip/hip_bf16.h>
#include <cstdint>

#define LH   50
#define PP   30
#define NAG  2048
#define EMBD 64
#define NHID 128
#define EHID 256
#define ADIM 64
#define CNND 2048

typedef __attribute__((ext_vector_type(8))) short bf16x8;
typedef __attribute__((ext_vector_type(4))) float f32x4;

enum : int {
  WS_C   = 0,                       // fp32 C [n][e]            524288
  WS_H0  = 524288,                  // bf16 H ping [n][e]       262144 float-slots
  WS_H1  = 786432,                  // bf16 H pong
  WS_WT  = 1048576,                 // bf16 WhhT [j=1024][e=256] 131072 float-slots
  WS_WFN = 1179648,                 // 2*1024 fused (W_nemb@Wih_n)
  WS_BFN = 1181696,                 // 1024
  WS_WFT = 1182720,                 // 2*512
  WS_BFT = 1183744,                 // 512
  WS_TH  = 1184256,                 // 128
  WS_TC  = 1184384,                 // 128
  WS_HT  = 1184512,                 // 256
  WS_W49 = 1184768,                 // 2048
  WS_CN  = 1186816,
  WS_POS = 1186817,
  WS_UA  = 1186819,
  WS_END = 1186822
};

__device__ __forceinline__ float sigf(float x){ return 1.0f/(1.0f + __expf(-x)); }
__device__ __forceinline__ float tanhfast(float x){
  x = fminf(15.0f, fmaxf(-15.0f, x));
  float e = __expf(2.0f*x);
  return (e - 1.0f)/(e + 1.0f);
}
__device__ __forceinline__ float bflo(unsigned u){ return __uint_as_float(u << 16); }
__device__ __forceinline__ float bfhi(unsigned u){ return __uint_as_float(u & 0xffff0000u); }

// ---- one-time: fold embeddings into gate weights ----------------------------
__global__ void k_setup(const float* __restrict__ Wnemb, const float* __restrict__ bnemb,
                        const float* __restrict__ Wihn,  const float* __restrict__ bihn,
                        const float* __restrict__ bhhn,
                        const float* __restrict__ Wtemb, const float* __restrict__ btemb,
                        const float* __restrict__ Wiht,  const float* __restrict__ biht,
                        const float* __restrict__ bhht,
                        float* __restrict__ ws)
{
  const int j = threadIdx.x;  // 1024
  {
    float a0=0.f, a1=0.f, ab=0.f;
    for (int k=0;k<EMBD;k++){
      const float w = Wihn[k*1024 + j];
      a0 += Wnemb[k]*w; a1 += Wnemb[EMBD+k]*w; ab += bnemb[k]*w;
    }
    ws[WS_WFN + j]        = a0;
    ws[WS_WFN + 1024 + j] = a1;
    ws[WS_BFN + j]        = ab + bihn[j] + bhhn[j];
  }
  if (j < 512){
    float a0=0.f, a1=0.f, ab=0.f;
    for (int k=0;k<EMBD;k++){
      const float w = Wiht[k*512 + j];
      a0 += Wtemb[k]*w; a1 += Wtemb[EMBD+k]*w; ab += btemb[k]*w;
    }
    ws[WS_WFT + j]       = a0;
    ws[WS_WFT + 512 + j] = a1;
    ws[WS_BFT + j]       = ab + biht[j] + bhht[j];
  }
}

// ---- one-time: Whh_n (256x1024 f32) -> WhhT (1024x256 bf16) -----------------
__global__ void k_transpose(const float* __restrict__ Whh, __hip_bfloat16* __restrict__ WT)
{
  __shared__ float t[32][33];
  const int tid = threadIdx.x;        // 256
  const int tx = tid & 31, ty = tid >> 5;  // ty in [0,8)
  const int j0 = blockIdx.x << 5;     // 32 blocks
  const int e0 = blockIdx.y << 5;     // 8 blocks
  #pragma unroll
  for (int r = 0; r < 4; ++r)
    t[ty + 8*r][tx] = Whh[(e0 + ty + 8*r)*1024 + j0 + tx];
  __syncthreads();
  #pragma unroll
  for (int r = 0; r < 4; ++r)
    WT[(j0 + ty + 8*r)*EHID + e0 + tx] = __float2bfloat16(t[tx][ty + 8*r]);
}

// ---- init H (bf16 [n][e]) / C (f32 [n][e]) / pos ----------------------------
__global__ void k_init(const float* __restrict__ nh0, const float* __restrict__ nc0,
                       const float* __restrict__ tpos,
                       float* __restrict__ Cst, __hip_bfloat16* __restrict__ H0,
                       float* __restrict__ ws)
{
  const int n = blockIdx.x, e = threadIdx.x;
  const int idx = n*EHID + e;
  H0[idx]  = __float2bfloat16(nh0[e]);
  Cst[idx] = nc0[e];
  if (idx == 0){ ws[WS_POS] = tpos[(LH-1)*2]; ws[WS_POS+1] = tpos[(LH-1)*2+1]; }
}

// ---- precompute obs-phase softmax weights at t = L-1 ------------------------
__global__ void k_att_pre(const float* __restrict__ tpos, const float* __restrict__ trel,
                          const float* __restrict__ npos, const int* __restrict__ nhist,
                          const float* __restrict__ Wtatt, const float* __restrict__ btatt,
                          const float* __restrict__ Wnatt, const float* __restrict__ bnatt,
                          float* __restrict__ ws)
{
  __shared__ float at[ADIM];
  __shared__ float red[256];
  __shared__ float uv[3];
  const int tid = threadIdx.x;   // 256
  const int t = LH - 1;
  const float tr0 = trel[2*t], tr1 = trel[2*t+1];
  const float tp0 = tpos[2*t], tp1 = tpos[2*t+1];
  if (tid < ADIM) at[tid] = tr0*Wtatt[tid] + tr1*Wtatt[ADIM+tid] + btatt[tid];
  int cnt = 0;
  for (int n = tid; n < NAG; n += 256) cnt += (nhist[n] > (LH - t)) ? 1 : 0;
  red[tid] = (float)cnt;
  __syncthreads();
  if (tid == 0){
    float u0=0.f,u1=0.f,v=0.f;
    for (int k=0;k<ADIM;k++){ u0 += Wnatt[k]*at[k]; u1 += Wnatt[ADIM+k]*at[k]; v += bnatt[k]*at[k]; }
    uv[0]=u0; uv[1]=u1; uv[2]=v;
  }
  for (int s=128; s>0; s>>=1){ if (tid < s) red[tid] += red[tid+s]; __syncthreads(); }
  const float currN = red[0];
  __syncthreads();
  const float u0 = uv[0], u1 = uv[1], v = uv[2];
  const float scale = currN * 0.125f;
  float sc[8]; float smax = -3.0e38f;
  #pragma unroll
  for (int i=0;i<8;i++){
    const int n = tid + 256*i;
    const float p0 = npos[n*(LH*2) + 2*t], p1 = npos[n*(LH*2) + 2*t + 1];
    float s = scale * ((tp0-p0)*u0 + (tp1-p1)*u1 + v);
    s = (nhist[n] > (LH - t)) ? s : -1.0e30f;
    sc[i] = s; smax = fmaxf(smax, s);
  }
  red[tid] = smax; __syncthreads();
  for (int s=128; s>0; s>>=1){ if (tid<s) red[tid] = fmaxf(red[tid], red[tid+s]); __syncthreads(); }
  smax = red[0]; __syncthreads();
  float ssum = 0.f;
  #pragma unroll
  for (int i=0;i<8;i++){ sc[i] = __expf(sc[i]-smax); ssum += sc[i]; }
  red[tid] = ssum; __syncthreads();
  for (int s=128; s>0; s>>=1){ if (tid<s) red[tid] += red[tid+s]; __syncthreads(); }
  const float inv = 1.0f / red[0];
  #pragma unroll
  for (int i=0;i<8;i++) ws[WS_W49 + tid + 256*i] = sc[i]*inv;
  if (tid == 0) ws[WS_CN] = currN;
}

// ---- entire obs-phase target LSTM, weights cached in VGPRs ------------------
__global__ __launch_bounds__(512) void k_target_obs(
    const float* __restrict__ trel, const int* __restrict__ thsp,
    const float* __restrict__ Whht,
    const float* __restrict__ th0, const float* __restrict__ tc0,
    float* __restrict__ ws)
{
  __shared__ __align__(16) float h[NHID];
  __shared__ float c[NHID], g[4*NHID];
  const int tid = threadIdx.x;   // 512
  const int ths = thsp[0];
  float w[NHID];
  #pragma unroll
  for (int k = 0; k < NHID; ++k) w[k] = Whht[k*(4*NHID) + tid];
  const float wf0 = ws[WS_WFT+tid], wf1 = ws[WS_WFT+512+tid], bft = ws[WS_BFT+tid];
  if (tid < NHID){ h[tid] = th0[tid]; c[tid] = tc0[tid]; }
  __syncthreads();
  for (int t = 1; t < LH; ++t){
    float acc = trel[2*t]*wf0 + trel[2*t+1]*wf1 + bft;
    const float4* h4 = (const float4*)h;
    #pragma unroll
    for (int k = 0; k < NHID/4; ++k){
      const float4 hv = h4[k];
      acc += hv.x*w[4*k] + hv.y*w[4*k+1] + hv.z*w[4*k+2] + hv.w*w[4*k+3];
    }
    g[tid] = acc;
    __syncthreads();
    if (tid < NHID && ths > LH - t){
      const float ig = sigf(g[tid]),            fg = sigf(g[NHID+tid]);
      const float gg = tanhfast(g[2*NHID+tid]), og = sigf(g[3*NHID+tid]);
      const float c2 = fg*c[tid] + ig*gg;
      c[tid] = c2; h[tid] = og*tanhfast(c2);
    }
    __syncthreads();
  }
  if (tid < NHID){ ws[WS_TH+tid] = h[tid]; ws[WS_TC+tid] = c[tid]; }
}

// ---- one nearby-LSTM step via MFMA ------------------------------------------
// G[n][j] = sum_e H[n][e] * WhhT[j][e]; j = gate*256 + e_out.
// Block: 4 waves x 16 agents = 64 agents, 16 e_out (x4 gates). Grid 32x16.
__launch_bounds__(256)
__global__ void k_nearby(const __hip_bfloat16* __restrict__ Hin,
                         __hip_bfloat16* __restrict__ Hout,
                         float* __restrict__ Cst,
                         const __hip_bfloat16* __restrict__ WT,
                         const float* __restrict__ wfn, const float* __restrict__ bfn,
                         const float* __restrict__ rel2, const int* __restrict__ nhist,
                         int thr)
{
  const int tid = threadIdx.x;
  const int wv = tid >> 6, lane = tid & 63;
  const int lhi = lane >> 4, llo = lane & 15;
  const int m0 = (blockIdx.x << 6) + (wv << 4);
  const int e0 = blockIdx.y << 4;

  const short* Hs = (const short*)Hin;
  const short* Ws = (const short*)WT;
  const short* ap  = Hs + (m0 + llo)*EHID + lhi*8;
  const short* bp0 = Ws + (          e0 + llo)*EHID + lhi*8;
  const short* bp1 = Ws + (1*256   + e0 + llo)*EHID + lhi*8;
  const short* bp2 = Ws + (2*256   + e0 + llo)*EHID + lhi*8;
  const short* bp3 = Ws + (3*256   + e0 + llo)*EHID + lhi*8;

  f32x4 acc0 = {0.f,0.f,0.f,0.f}, acc1 = acc0, acc2 = acc0, acc3 = acc0;
  #pragma unroll
  for (int kk = 0; kk < 8; ++kk){
    const int ko = kk*32;
    const bf16x8 a = *(const bf16x8*)(ap + ko);
    acc0 = __builtin_amdgcn_mfma_f32_16x16x32_bf16(a, *(const bf16x8*)(bp0 + ko), acc0, 0,0,0);
    acc1 = __builtin_amdgcn_mfma_f32_16x16x32_bf16(a, *(const bf16x8*)(bp1 + ko), acc1, 0,0,0);
    acc2 = __builtin_amdgcn_mfma_f32_16x16x32_bf16(a, *(const bf16x8*)(bp2 + ko), acc2, 0,0,0);
    acc3 = __builtin_amdgcn_mfma_f32_16x16x32_bf16(a, *(const bf16x8*)(bp3 + ko), acc3, 0,0,0);
  }

  const int eo = e0 + llo;
  const float wi0 = wfn[eo],       wi1 = wfn[1024+eo],       bi = bfn[eo];
  const float wfa = wfn[256+eo],   wfb = wfn[1024+256+eo],   bfv = bfn[256+eo];
  const float wg0 = wfn[512+eo],   wg1 = wfn[1024+512+eo],   bg = bfn[512+eo];
  const float wo0 = wfn[768+eo],   wo1 = wfn[1024+768+eo],   bo = bfn[768+eo];
  #pragma unroll
  for (int r = 0; r < 4; ++r){
    const int n = m0 + lhi*4 + r;
    const float r0 = rel2[n*(LH*2)], r1 = rel2[n*(LH*2)+1];
    const bool msk = nhist[n] > thr;
    const int off = n*EHID + eo;
    const float co = Cst[off];
    const float ho = __bfloat162float(Hin[off]);
    const float gi = acc0[r] + r0*wi0 + r1*wi1 + bi;
    const float gf = acc1[r] + r0*wfa + r1*wfb + bfv;
    const float gg = acc2[r] + r0*wg0 + r1*wg1 + bg;
    const float go = acc3[r] + r0*wo0 + r1*wo1 + bo;
    const float c2 = sigf(gf)*co + sigf(gi)*tanhfast(gg);
    const float h2 = sigf(go)*tanhfast(c2);
    Cst[off]  = msk ? c2 : co;
    Hout[off] = __float2bfloat16(msk ? h2 : ho);
  }
}

// ---- final obs attention: Ht = w49 @ H  (or h0 fallback) --------------------
__global__ void k_att_obs(const __hip_bfloat16* __restrict__ Hcur,
                          const float* __restrict__ nh0, float* __restrict__ ws)
{
  __shared__ float part[16*EHID];
  const int tid = threadIdx.x;            // 1024
  const int lane = tid & 63, wv = tid >> 6;
  const float currN = ws[WS_CN];
  if (currN >= 1.0f){
    const short* Hs = (const short*)Hcur;
    float a0=0.f,a1=0.f,a2=0.f,a3=0.f;
    const int nEnd = wv*128 + 128;
    #pragma unroll 4
    for (int n = wv*128; n < nEnd; ++n){
      const float wgt = ws[WS_W49 + n];
      const uint2 hv = *(const uint2*)(Hs + n*EHID + lane*4);
      a0 += wgt*bflo(hv.x); a1 += wgt*bfhi(hv.x);
      a2 += wgt*bflo(hv.y); a3 += wgt*bfhi(hv.y);
    }
    float* p = part + wv*EHID + lane*4;
    p[0]=a0; p[1]=a1; p[2]=a2; p[3]=a3;
    __syncthreads();
    if (tid < EHID){
      float s = 0.f;
      #pragma unroll
      for (int w2 = 0; w2 < 16; ++w2) s += part[w2*EHID + tid];
      ws[WS_HT + tid] = s;
    }
  } else {
    if (tid < EHID) ws[WS_HT + tid] = nh0[tid];
  }
}

__device__ __forceinline__ float bredSum(float v, volatile float* tmp, int tid){
  const int lane = tid & 63, wv = tid >> 6;
  #pragma unroll
  for (int o = 32; o > 0; o >>= 1) v += __shfl_down(v, o, 64);
  if (lane == 0) tmp[wv] = v;
  __syncthreads();
  if (tid == 0){
    float s = 0.f;
    for (int i = 0; i < 16; ++i) s += tmp[i];
    tmp[16] = s;
  }
  __syncthreads();
  return tmp[16];
}
__device__ __forceinline__ float bredMax(float v, volatile float* tmp, int tid){
  const int lane = tid & 63, wv = tid >> 6;
  #pragma unroll
  for (int o = 32; o > 0; o >>= 1) v = fmaxf(v, __shfl_down(v, o, 64));
  if (lane == 0) tmp[wv] = v;
  __syncthreads();
  if (tid == 0){
    float s = -3.0e38f;
    for (int i = 0; i < 16; ++i) s = fmaxf(s, tmp[i]);
    tmp[16] = s;
  }
  __syncthreads();
  return tmp[16];
}

// ---- pred-phase fused: [attention(prev)] -> pred -> pos -> tLSTM -> u,A -----
__global__ void k_attpred(const __hip_bfloat16* __restrict__ Hcur, int sidx, int do_att,
                          const float* __restrict__ img, const float* __restrict__ npos,
                          const float* __restrict__ Wpred, const float* __restrict__ bpred,
                          const float* __restrict__ Wtatt, const float* __restrict__ btatt,
                          const float* __restrict__ Wnatt, const float* __restrict__ bnatt,
                          const float* __restrict__ Whht,
                          float* __restrict__ ws, float* __restrict__ out)
{
  __shared__ float wsm[NAG];
  __shared__ float part[16*EHID];
  __shared__ float rtmp[17];
  __shared__ float ht[EHID];
  __shared__ float at[ADIM];
  __shared__ float gl[4*NHID];
  __shared__ float thl[NHID], tcl[NHID];
  __shared__ float pv[4];
  const int tid = threadIdx.x;      // 1024
  const int lane = tid & 63, wv = tid >> 6;

  if (do_att){
    const float u0 = ws[WS_UA], u1 = ws[WS_UA+1], A = ws[WS_UA+2];
    float sc0, sc1;
    {
      int n = tid;
      float p0 = npos[n*(LH*2) + (LH-1)*2], p1 = npos[n*(LH*2) + (LH-1)*2 + 1];
      sc0 = 256.0f * (A - (p0*u0 + p1*u1));
      n = tid + 1024;
      p0 = npos[n*(LH*2) + (LH-1)*2]; p1 = npos[n*(LH*2) + (LH-1)*2 + 1];
      sc1 = 256.0f * (A - (p0*u0 + p1*u1));
    }
    const float smax = bredMax(fmaxf(sc0, sc1), rtmp, tid);
    const float ex0 = __expf(sc0 - smax), ex1 = __expf(sc1 - smax);
    wsm[tid] = ex0; wsm[tid+1024] = ex1;
    const float ssum = bredSum(ex0 + ex1, rtmp, tid);
    const float inv = 1.0f / ssum;
    __syncthreads();   // wsm visible to all
    const short* Hs = (const short*)Hcur;
    float a0=0.f,a1=0.f,a2=0.f,a3=0.f;
    const int nEnd = wv*128 + 128;
    #pragma unroll 4
    for (int n = wv*128; n < nEnd; ++n){
      const float wgt = wsm[n];
      const uint2 hv = *(const uint2*)(Hs + n*EHID + lane*4);
      a0 += wgt*bflo(hv.x); a1 += wgt*bfhi(hv.x);
      a2 += wgt*bflo(hv.y); a3 += wgt*bfhi(hv.y);
    }
    float* p = part + wv*EHID + lane*4;
    p[0]=a0; p[1]=a1; p[2]=a2; p[3]=a3;
    __syncthreads();
    if (tid < EHID){
      float s = 0.f;
      #pragma unroll
      for (int w2 = 0; w2 < 16; ++w2) s += part[w2*EHID + tid];
      s *= inv;
      ht[tid] = s; ws[WS_HT + tid] = s;
    }
  } else {
    if (tid < EHID) ht[tid] = ws[WS_HT + tid];
  }
  if (tid < NHID){ thl[tid] = ws[WS_TH + tid]; tcl[tid] = ws[WS_TC + tid]; }
  __syncthreads();
  // pred head: [th, img, Ht] @ W_pred + b_pred
  float a0 = 0.f, a1 = 0.f;
  for (int k = tid; k < NHID+CNND+EHID; k += 1024){
    const float v = (k < NHID) ? thl[k] : ((k < NHID+CNND) ? img[k-NHID] : ht[k-NHID-CNND]);
    a0 += v * Wpred[2*k];
    a1 += v * Wpred[2*k+1];
  }
  a0 = bredSum(a0, rtmp, tid);
  a1 = bredSum(a1, rtmp, tid);
  if (tid == 0){
    const float p0 = a0 + bpred[0], p1 = a1 + bpred[1];
    out[2*sidx] = p0; out[2*sidx+1] = p1;
    const float q0 = ws[WS_POS] + p0, q1 = ws[WS_POS+1] + p1;
    ws[WS_POS] = q0; ws[WS_POS+1] = q1;
    pv[0]=p0; pv[1]=p1; pv[2]=q0; pv[3]=q1;
  }
  __syncthreads();
  if (tid < ADIM) at[tid] = pv[0]*Wtatt[tid] + pv[1]*Wtatt[ADIM+tid] + btatt[tid];
  __syncthreads();
  if (tid == 0){
    float u0=0.f,u1=0.f,v=0.f;
    for (int k=0;k<ADIM;k++){ u0 += Wnatt[k]*at[k]; u1 += Wnatt[ADIM+k]*at[k]; v += bnatt[k]*at[k]; }
    ws[WS_UA] = u0; ws[WS_UA+1] = u1; ws[WS_UA+2] = pv[2]*u0 + pv[3]*u1 + v;
  }
  if (tid < 4*NHID){
    float g = pv[0]*ws[WS_WFT+tid] + pv[1]*ws[WS_WFT+512+tid] + ws[WS_BFT+tid];
    for (int k = 0; k < NHID; ++k) g += thl[k]*Whht[k*(4*NHID)+tid];
    gl[tid] = g;
  }
  __syncthreads();
  if (tid < NHID){
    const float ig = sigf(gl[tid]),            fg = sigf(gl[NHID+tid]);
    const float gg = tanhfast(gl[2*NHID+tid]), og = sigf(gl[3*NHID+tid]);
    const float c2 = fg*tcl[tid] + ig*gg;
    ws[WS_TC+tid] = c2;
    ws[WS_TH+tid] = og*tanhfast(c2);
  }
}

extern "C" void kernel_launch(void* const* d_in, const int* in_sizes, int n_in,
                              void* d_out, int out_size, void* d_ws, size_t ws_size,
                              hipStream_t stream) {
  const float* img   = (const float*)d_in[0];
  const float* tpos  = (const float*)d_in[1];
  const float* trel  = (const float*)d_in[2];
  const float* npos  = (const float*)d_in[3];
  const float* nrel  = (const float*)d_in[4];
  const int*   nhist = (const int*)d_in[5];
  const int*   ths   = (const int*)d_in[6];
  const float* th0   = (const float*)d_in[7];
  const float* tc0   = (const float*)d_in[8];
  const float* Wtemb = (const float*)d_in[9];
  const float* btemb = (const float*)d_in[10];
  const float* Wiht  = (const float*)d_in[11];
  const float* Whht  = (const float*)d_in[12];
  const float* biht  = (const float*)d_in[13];
  const float* bhht  = (const float*)d_in[14];
  const float* Wtatt = (const float*)d_in[15];
  const float* btatt = (const float*)d_in[16];
  const float* nh0   = (const float*)d_in[17];
  const float* nc0   = (const float*)d_in[18];
  const float* Wnemb = (const float*)d_in[19];
  const float* bnemb = (const float*)d_in[20];
  const float* Wihn  = (const float*)d_in[21];
  const float* Whhn  = (const float*)d_in[22];
  const float* bihn  = (const float*)d_in[23];
  const float* bhhn  = (const float*)d_in[24];
  const float* Wnatt = (const float*)d_in[25];
  const float* bnatt = (const float*)d_in[26];
  const float* Wpred = (const float*)d_in[27];
  const float* bpred = (const float*)d_in[28];
  float* ws  = (float*)d_ws;
  float* out = (float*)d_out;

  float* Cst = ws + WS_C;
  __hip_bfloat16* H0 = (__hip_bfloat16*)(ws + WS_H0);
  __hip_bfloat16* H1 = (__hip_bfloat16*)(ws + WS_H1);
  __hip_bfloat16* WT = (__hip_bfloat16*)(ws + WS_WT);
  __hip_bfloat16* Hb[2] = { H0, H1 };

  k_setup<<<1, 1024, 0, stream>>>(Wnemb, bnemb, Wihn, bihn, bhhn,
                                  Wtemb, btemb, Wiht, biht, bhht, ws);
  k_transpose<<<dim3(32,8), 256, 0, stream>>>(Whhn, WT);
  k_init<<<NAG, EHID, 0, stream>>>(nh0, nc0, tpos, Cst, H0, ws);
  k_att_pre<<<1, 256, 0, stream>>>(tpos, trel, npos, nhist, Wtatt, btatt, Wnatt, bnatt, ws);
  k_target_obs<<<1, 512, 0, stream>>>(trel, ths, Whht, th0, tc0, ws);

  for (int t = 1; t < LH; ++t){
    k_nearby<<<dim3(32,16), 256, 0, stream>>>(Hb[(t-1)&1], Hb[t&1], Cst, WT,
                                              ws + WS_WFN, ws + WS_BFN,
                                              nrel + 2*t, nhist, LH - t);
  }
  k_att_obs<<<1, 1024, 0, stream>>>(Hb[(LH-1)&1], nh0, ws);

  k_attpred<<<1, 1024, 0, stream>>>(Hb[(LH-1)&1], 0, 0, img, npos,
                                    Wpred, bpred, Wtatt, btatt, Wnatt, bnatt, Whht, ws, out);
  for (int s = 0; s < PP-1; ++s){
    k_nearby<<<dim3(32,16), 256, 0, stream>>>(Hb[(LH-1+s)&1], Hb[(LH+s)&1], Cst, WT,
                                              ws + WS_WFN, ws + WS_BFN,
                                              nrel + 2*(LH-1), nhist, -1);
    k_attpred<<<1, 1024, 0, stream>>>(Hb[(LH+s)&1], s+1, 1, img, npos,
                                      Wpred, bpred, Wtatt, btatt, Wnatt, bnatt, Whht, ws, out);
  }
}

// Round 4
// 1679.016 us; speedup vs baseline: 2.1968x; 1.0491x over previous
//
#include <hip/hip_runtime.h>
#include <hip/hip_bf16.h>
#include <cstdint>

#define LH   50
#define PP   30
#define NAG  2048
#define NHID 128
#define EHID 256
#define ADIM 64
#define CNND 2048

typedef __attribute__((ext_vector_type(8))) short bf16x8;
typedef __attribute__((ext_vector_type(4))) float f32x4;

// ---- workspace layout (float slots) -----------------------------------------
enum : int {
  WS_WT  = 0,        // bf16 WhhT[1024][256]      -> 131072 float slots
  WS_WHT = 131072,   // bf16 WhtT[512][128]       -> 32768
  WS_WFN = 163840,   // 2*1024 folded (W_nemb@Wih_n)
  WS_BFN = 165888,   // 1024
  WS_WFT = 166912,   // 2*512 folded (W_temb@Wih_t)
  WS_BFT = 167936,   // 512
  WS_TH  = 168448,   // 128  (th after obs chain)
  WS_TC  = 168576,   // 128
  WS_W49 = 168704,   // 2048 obs softmax weights
  WS_CN  = 170752,   // 1    currN(49)
  WS_Z   = 170756,   // 30*2048*2 = 122880
  WS_END = 293636
};

__device__ __forceinline__ float sigf(float x){ return 1.0f/(1.0f + __expf(-x)); }
__device__ __forceinline__ float tanhfast(float x){
  x = fminf(15.0f, fmaxf(-15.0f, x));
  float e = __expf(2.0f*x);
  return (e - 1.0f)/(e + 1.0f);
}
__device__ __forceinline__ float bfs(short s){
  return __uint_as_float(((unsigned)(unsigned short)s) << 16);
}

// ---- prep: WhhT (bf16), WhtT (bf16), folded gate weights ---------------------
// grid 257 x 256: blocks 0..255 transpose Whh_n; block 256 does folds + WhtT.
__global__ void k_prep(const float* __restrict__ Whhn, const float* __restrict__ Whht,
                       const float* __restrict__ Wnemb, const float* __restrict__ bnemb,
                       const float* __restrict__ Wihn,  const float* __restrict__ bihn,
                       const float* __restrict__ bhhn,
                       const float* __restrict__ Wtemb, const float* __restrict__ btemb,
                       const float* __restrict__ Wiht,  const float* __restrict__ biht,
                       const float* __restrict__ bhht,
                       float* __restrict__ ws)
{
  const int b = blockIdx.x, tid = threadIdx.x;
  if (b < 256){
    __shared__ float t[32][33];
    __hip_bfloat16* WT = (__hip_bfloat16*)(ws + WS_WT);
    const int tx = tid & 31, ty = tid >> 5;     // ty in [0,8)
    const int j0 = (b & 31) << 5;
    const int e0 = (b >> 5) << 5;
    #pragma unroll
    for (int r = 0; r < 4; ++r)
      t[ty + 8*r][tx] = Whhn[(e0 + ty + 8*r)*1024 + j0 + tx];
    __syncthreads();
    #pragma unroll
    for (int r = 0; r < 4; ++r)
      WT[(j0 + ty + 8*r)*EHID + e0 + tx] = __float2bfloat16(t[tx][ty + 8*r]);
  } else {
    // nearby folds
    for (int j = tid; j < 1024; j += 256){
      float a0=0.f, a1=0.f, ab=0.f;
      for (int k=0;k<64;k++){
        const float w = Wihn[k*1024 + j];
        a0 += Wnemb[k]*w; a1 += Wnemb[64+k]*w; ab += bnemb[k]*w;
      }
      ws[WS_WFN + j]        = a0;
      ws[WS_WFN + 1024 + j] = a1;
      ws[WS_BFN + j]        = ab + bihn[j] + bhhn[j];
    }
    // target folds
    for (int j = tid; j < 512; j += 256){
      float a0=0.f, a1=0.f, ab=0.f;
      for (int k=0;k<64;k++){
        const float w = Wiht[k*512 + j];
        a0 += Wtemb[k]*w; a1 += Wtemb[64+k]*w; ab += btemb[k]*w;
      }
      ws[WS_WFT + j]       = a0;
      ws[WS_WFT + 512 + j] = a1;
      ws[WS_BFT + j]       = ab + biht[j] + bhht[j];
    }
    // WhtT bf16 [j=512][k=128]
    __hip_bfloat16* WTt = (__hip_bfloat16*)(ws + WS_WHT);
    for (int j = tid; j < 512; j += 256)
      for (int k = 0; k < 128; ++k)
        WTt[j*128 + k] = __float2bfloat16(Whht[k*512 + j]);
  }
}

// ---- Phase A: whole 78-step nearby chain (blocks 0..127) + target obs chain
//      (block 128) + w49 precompute (block 129). One launch.
__global__ __launch_bounds__(256, 1) void k_phaseA(
    const float* __restrict__ nh0, const float* __restrict__ nc0,
    const float* __restrict__ nrel, const int* __restrict__ nhist,
    const float* __restrict__ Wpred,
    const float* __restrict__ trel, const int* __restrict__ thsp,
    const float* __restrict__ Whht, const float* __restrict__ th0,
    const float* __restrict__ tc0,
    const float* __restrict__ tpos, const float* __restrict__ npos,
    const float* __restrict__ Wtatt, const float* __restrict__ btatt,
    const float* __restrict__ Wnatt, const float* __restrict__ bnatt,
    float* __restrict__ ws)
{
  __shared__ float smem[4224];
  const int b = blockIdx.x, tid = threadIdx.x;

  if (b < 128){
    // ---- nearby LSTM: 16 agents, all 78 steps internal ----
    __hip_bfloat16* Hl = (__hip_bfloat16*)smem;      // [16][264] bf16 (2112 fl)
    float* relS = smem + 2112;                        // [16][50][2]
    float* vS   = smem + 3712;                        // [256][2]
    const int lane = tid & 63, wv = tid >> 6;
    const int lhi = lane >> 4, llo = lane & 15;
    const int n0 = b << 4;

    for (int i = tid; i < 1600; i += 256){
      const int a = i / 100, r = i % 100;
      relS[a*100 + r] = nrel[(n0 + a)*100 + r];
    }
    {
      const int e = tid;
      if (e < 256){
        vS[2*e]   = Wpred[2*(NHID + CNND + e)];
        vS[2*e+1] = Wpred[2*(NHID + CNND + e) + 1];
      }
    }
    for (int i = tid; i < 16*256; i += 256){
      const int a = i >> 8, e = i & 255;
      Hl[a*264 + e] = __float2bfloat16(nh0[e]);
    }

    // per-thread: (agent = lhi*4+r, eo = wv*64 + ct*16 + llo)
    float C[4][4], ho[4][4];
    float wf0[4][4], wf1[4][4], wb[4][4];
    #pragma unroll
    for (int g = 0; g < 4; ++g)
      #pragma unroll
      for (int ct = 0; ct < 4; ++ct){
        const int j = g*256 + wv*64 + ct*16 + llo;
        wf0[g][ct] = ws[WS_WFN + j];
        wf1[g][ct] = ws[WS_WFN + 1024 + j];
        wb [g][ct] = ws[WS_BFN + j];
      }
    #pragma unroll
    for (int r = 0; r < 4; ++r)
      #pragma unroll
      for (int ct = 0; ct < 4; ++ct){
        const int eo = wv*64 + ct*16 + llo;
        C[r][ct]  = nc0[eo];
        ho[r][ct] = nh0[eo];
      }
    int nh4[4];
    #pragma unroll
    for (int r = 0; r < 4; ++r) nh4[r] = nhist[n0 + lhi*4 + r];

    const short* Wb = (const short*)(ws + WS_WT);
    __syncthreads();

    for (int st = 1; st <= 78; ++st){
      const int thr  = (st <= 49) ? (50 - st) : -1;
      const int tsel = (st <= 49) ? st : 49;

      bf16x8 af[8];
      const short* hrow = (const short*)Hl + llo*264 + lhi*8;
      #pragma unroll
      for (int kk = 0; kk < 8; ++kk) af[kk] = *(const bf16x8*)(hrow + kk*32);

      f32x4 acc[4][4];
      #pragma unroll
      for (int g = 0; g < 4; ++g)
        #pragma unroll
        for (int ct = 0; ct < 4; ++ct) acc[g][ct] = (f32x4){0.f,0.f,0.f,0.f};

      #pragma unroll
      for (int kk = 0; kk < 8; ++kk){
        #pragma unroll
        for (int g = 0; g < 4; ++g)
          #pragma unroll
          for (int ct = 0; ct < 4; ++ct){
            const int j = g*256 + wv*64 + ct*16 + llo;
            const bf16x8 bf = *(const bf16x8*)(Wb + j*256 + kk*32 + lhi*8);
            acc[g][ct] = __builtin_amdgcn_mfma_f32_16x16x32_bf16(af[kk], bf, acc[g][ct], 0,0,0);
          }
      }

      #pragma unroll
      for (int r = 0; r < 4; ++r){
        const float r0 = relS[(lhi*4 + r)*100 + 2*tsel];
        const float r1 = relS[(lhi*4 + r)*100 + 2*tsel + 1];
        const bool mk = nh4[r] > thr;
        #pragma unroll
        for (int ct = 0; ct < 4; ++ct){
          const float gi = acc[0][ct][r] + r0*wf0[0][ct] + r1*wf1[0][ct] + wb[0][ct];
          const float gf = acc[1][ct][r] + r0*wf0[1][ct] + r1*wf1[1][ct] + wb[1][ct];
          const float gg = acc[2][ct][r] + r0*wf0[2][ct] + r1*wf1[2][ct] + wb[2][ct];
          const float go = acc[3][ct][r] + r0*wf0[3][ct] + r1*wf1[3][ct] + wb[3][ct];
          const float c2 = sigf(gf)*C[r][ct] + sigf(gi)*tanhfast(gg);
          const float h2 = sigf(go)*tanhfast(c2);
          if (mk){ C[r][ct] = c2; ho[r][ct] = h2; }
        }
      }
      __syncthreads();   // everyone done reading Hl (A-frags)
      #pragma unroll
      for (int r = 0; r < 4; ++r)
        #pragma unroll
        for (int ct = 0; ct < 4; ++ct)
          Hl[(lhi*4 + r)*264 + wv*64 + ct*16 + llo] = __float2bfloat16(ho[r][ct]);
      __syncthreads();   // Hl updated

      if (st >= 49){
        const int s = st - 49;
        const int a = tid >> 4, sg = tid & 15;
        float z0 = 0.f, z1 = 0.f;
        for (int e = sg*16; e < sg*16 + 16; ++e){
          const float h = __bfloat162float(Hl[a*264 + e]);
          z0 += h*vS[2*e]; z1 += h*vS[2*e+1];
        }
        z0 += __shfl_xor(z0, 1, 64); z1 += __shfl_xor(z1, 1, 64);
        z0 += __shfl_xor(z0, 2, 64); z1 += __shfl_xor(z1, 2, 64);
        z0 += __shfl_xor(z0, 4, 64); z1 += __shfl_xor(z1, 4, 64);
        z0 += __shfl_xor(z0, 8, 64); z1 += __shfl_xor(z1, 8, 64);
        if (sg == 0){
          ws[WS_Z + (s*NAG + n0 + a)*2]     = z0;
          ws[WS_Z + (s*NAG + n0 + a)*2 + 1] = z1;
        }
      }
    }
  }
  else if (b == 128){
    // ---- target obs chain (49 steps), 256 threads x 2 gate cols ----
    float* hT = smem; float* cT = smem + 128; float* gT = smem + 256;  // 512
    if (tid < 128){ hT[tid] = th0[tid]; cT[tid] = tc0[tid]; }
    __syncthreads();
    const int ths = thsp[0];
    for (int t = 1; t < 50; ++t){
      const float x0 = trel[2*t], x1 = trel[2*t+1];
      #pragma unroll
      for (int q = 0; q < 2; ++q){
        const int j = tid + q*256;
        float acc = x0*ws[WS_WFT + j] + x1*ws[WS_WFT + 512 + j] + ws[WS_BFT + j];
        for (int k = 0; k < 128; ++k) acc += hT[k]*Whht[k*512 + j];
        gT[j] = acc;
      }
      __syncthreads();
      if (tid < 128 && ths > 50 - t){
        const float ig = sigf(gT[tid]),        fg = sigf(gT[128 + tid]);
        const float gg = tanhfast(gT[256+tid]), og = sigf(gT[384 + tid]);
        const float c2 = fg*cT[tid] + ig*gg;
        cT[tid] = c2; hT[tid] = og*tanhfast(c2);
      }
      __syncthreads();
    }
    if (tid < 128){ ws[WS_TH + tid] = hT[tid]; ws[WS_TC + tid] = cT[tid]; }
  }
  else {
    // ---- w49 precompute (obs-final attention weights) ----
    float* at  = smem;          // 64
    float* red = smem + 64;     // 256
    float* uv  = smem + 320;    // 3
    const int t = LH - 1;
    const float tr0 = trel[2*t], tr1 = trel[2*t+1];
    const float tp0 = tpos[2*t], tp1 = tpos[2*t+1];
    if (tid < ADIM) at[tid] = tr0*Wtatt[tid] + tr1*Wtatt[ADIM+tid] + btatt[tid];
    int cnt = 0;
    for (int n = tid; n < NAG; n += 256) cnt += (nhist[n] > (LH - t)) ? 1 : 0;
    red[tid] = (float)cnt;
    __syncthreads();
    if (tid == 0){
      float u0=0.f,u1=0.f,v=0.f;
      for (int k=0;k<ADIM;k++){ u0 += Wnatt[k]*at[k]; u1 += Wnatt[ADIM+k]*at[k]; v += bnatt[k]*at[k]; }
      uv[0]=u0; uv[1]=u1; uv[2]=v;
    }
    for (int s=128; s>0; s>>=1){ if (tid < s) red[tid] += red[tid+s]; __syncthreads(); }
    const float currN = red[0];
    __syncthreads();
    const float u0 = uv[0], u1 = uv[1], v = uv[2];
    const float scale = currN * 0.125f;
    float sc[8]; float smax = -3.0e38f;
    #pragma unroll
    for (int i=0;i<8;i++){
      const int n = tid + 256*i;
      const float p0 = npos[n*100 + 2*t], p1 = npos[n*100 + 2*t + 1];
      float s = scale * ((tp0-p0)*u0 + (tp1-p1)*u1 + v);
      s = (nhist[n] > (LH - t)) ? s : -1.0e30f;
      sc[i] = s; smax = fmaxf(smax, s);
    }
    red[tid] = smax; __syncthreads();
    for (int s=128; s>0; s>>=1){ if (tid<s) red[tid] = fmaxf(red[tid], red[tid+s]); __syncthreads(); }
    smax = red[0]; __syncthreads();
    float ssum = 0.f;
    #pragma unroll
    for (int i=0;i<8;i++){ sc[i] = __expf(sc[i]-smax); ssum += sc[i]; }
    red[tid] = ssum; __syncthreads();
    for (int s=128; s>0; s>>=1){ if (tid<s) red[tid] += red[tid+s]; __syncthreads(); }
    const float inv = 1.0f / red[0];
    #pragma unroll
    for (int i=0;i<8;i++) ws[WS_W49 + tid + 256*i] = sc[i]*inv;
    if (tid == 0) ws[WS_CN] = currN;
  }
}

// ---- Phase B: all 30 pred steps in one block ---------------------------------
template<int K>
__device__ __forceinline__ void bredN(const float* v, volatile float* scratch,
                                      volatile float* outv, int tid){
  const int lane = tid & 63, wv = tid >> 6;
  #pragma unroll
  for (int k = 0; k < K; ++k){
    float x = v[k];
    #pragma unroll
    for (int o = 32; o > 0; o >>= 1) x += __shfl_down(x, o, 64);
    if (lane == 0) scratch[k*8 + wv] = x;
  }
  __syncthreads();
  if (tid == 0){
    #pragma unroll
    for (int k = 0; k < K; ++k){
      float s = 0.f;
      for (int i = 0; i < 8; ++i) s += scratch[k*8 + i];
      outv[k] = s;
    }
  }
  __syncthreads();
}

__device__ __forceinline__ float bredMax1(float x, volatile float* scratch,
                                          volatile float* outv, int tid){
  const int lane = tid & 63, wv = tid >> 6;
  #pragma unroll
  for (int o = 32; o > 0; o >>= 1) x = fmaxf(x, __shfl_down(x, o, 64));
  if (lane == 0) scratch[wv] = x;
  __syncthreads();
  if (tid == 0){
    float s = -3.0e38f;
    for (int i = 0; i < 8; ++i) s = fmaxf(s, scratch[i]);
    outv[0] = s;
  }
  __syncthreads();
  return outv[0];
}

__global__ __launch_bounds__(512, 1) void k_phaseB(
    const float* __restrict__ img, const float* __restrict__ tpos,
    const float* __restrict__ npos, const float* __restrict__ nh0,
    const float* __restrict__ Wpred, const float* __restrict__ bpred,
    const float* __restrict__ Wtatt, const float* __restrict__ btatt,
    const float* __restrict__ Wnatt, const float* __restrict__ bnatt,
    float* __restrict__ ws, float* __restrict__ out)
{
  __shared__ float p0s[NAG], p1s[NAG];
  __shared__ float th[128], tc[128], gl[512], at[64];
  __shared__ float scratch[24];
  __shared__ float bc[8];
  const int tid = threadIdx.x, lane = tid & 63, wv = tid >> 6;

  // Whht columns (bf16) cached in VGPRs: col j = tid
  bf16x8 wreg[16];
  {
    const short* wp = (const short*)(ws + WS_WHT) + tid*128;
    #pragma unroll
    for (int f = 0; f < 16; ++f) wreg[f] = *(const bf16x8*)(wp + f*8);
  }
  for (int n = tid; n < NAG; n += 512){
    p0s[n] = npos[n*100 + 98];
    p1s[n] = npos[n*100 + 99];
  }
  if (tid < 128){ th[tid] = ws[WS_TH + tid]; tc[tid] = ws[WS_TC + tid]; }

  // img @ Wpred (constant part), nh0·v fallback
  {
    float v[2] = {0.f, 0.f};
    for (int k = tid; k < CNND; k += 512){
      v[0] += img[k]*Wpred[2*(128 + k)];
      v[1] += img[k]*Wpred[2*(128 + k) + 1];
    }
    bredN<2>(v, scratch, bc, tid);
  }
  const float imgW0 = bc[0], imgW1 = bc[1];
  {
    float v[2] = {0.f, 0.f};
    if (tid < 256){
      v[0] = nh0[tid]*Wpred[2*(128 + CNND + tid)];
      v[1] = nh0[tid]*Wpred[2*(128 + CNND + tid) + 1];
    }
    bredN<2>(v, scratch, bc + 2, tid);
  }
  const float fb0 = bc[2], fb1 = bc[3];
  const float currN = ws[WS_CN];
  float pos0 = tpos[98], pos1 = tpos[99];
  float u0 = 0.f, u1 = 0.f, A = 0.f;
  __syncthreads();

  for (int s = 0; s < PP; ++s){
    const float* zs = ws + WS_Z + s*(NAG*2);
    float hv0, hv1;
    if (s == 0){
      if (currN >= 1.0f){
        float v[2] = {0.f, 0.f};
        for (int n = tid; n < NAG; n += 512){
          const float w = ws[WS_W49 + n];
          v[0] += w*zs[2*n]; v[1] += w*zs[2*n + 1];
        }
        bredN<2>(v, scratch, bc, tid);
        hv0 = bc[0]; hv1 = bc[1];
      } else { hv0 = fb0; hv1 = fb1; }
    } else {
      float sc[4], mx = -3.0e38f;
      #pragma unroll
      for (int i = 0; i < 4; ++i){
        const int n = tid + 512*i;
        sc[i] = 256.0f * (A - (p0s[n]*u0 + p1s[n]*u1));
        mx = fmaxf(mx, sc[i]);
      }
      mx = bredMax1(mx, scratch, bc + 7, tid);
      float v[3] = {0.f, 0.f, 0.f};
      #pragma unroll
      for (int i = 0; i < 4; ++i){
        const int n = tid + 512*i;
        const float e = __expf(sc[i] - mx);
        v[0] += e; v[1] += e*zs[2*n]; v[2] += e*zs[2*n + 1];
      }
      bredN<3>(v, scratch, bc, tid);
      const float inv = 1.0f / bc[0];
      hv0 = bc[1]*inv; hv1 = bc[2]*inv;
    }
    // th @ Wpred (first 128 rows)
    {
      float v[2] = {0.f, 0.f};
      if (tid < 128){
        v[0] = th[tid]*Wpred[2*tid];
        v[1] = th[tid]*Wpred[2*tid + 1];
      }
      bredN<2>(v, scratch, bc + 2, tid);
    }
    const float pr0 = bc[2] + imgW0 + hv0 + bpred[0];
    const float pr1 = bc[3] + imgW1 + hv1 + bpred[1];
    if (tid == 0){ out[2*s] = pr0; out[2*s + 1] = pr1; }
    pos0 += pr0; pos1 += pr1;

    // target LSTM step (x = pred); gate col j = tid
    {
      float g = pr0*ws[WS_WFT + tid] + pr1*ws[WS_WFT + 512 + tid] + ws[WS_BFT + tid];
      #pragma unroll
      for (int f = 0; f < 16; ++f){
        #pragma unroll
        for (int i = 0; i < 8; ++i)
          g += bfs(wreg[f][i]) * th[f*8 + i];
      }
      gl[tid] = g;
    }
    __syncthreads();
    float hnew = 0.f, cnew = 0.f;
    if (tid < 128){
      const float ig = sigf(gl[tid]),          fg = sigf(gl[128 + tid]);
      const float gg = tanhfast(gl[256 + tid]), og = sigf(gl[384 + tid]);
      cnew = fg*tc[tid] + ig*gg;
      hnew = og*tanhfast(cnew);
    }
    __syncthreads();   // all gl reads done before th/tc overwritten
    if (tid < 128){ th[tid] = hnew; tc[tid] = cnew; }

    // next-step u, A  (at computed and consumed by wave 0)
    if (tid < ADIM) at[tid] = pr0*Wtatt[tid] + pr1*Wtatt[ADIM + tid] + btatt[tid];
    __syncthreads();
    if (wv == 0){
      float uu0 = Wnatt[lane]*at[lane];
      float uu1 = Wnatt[ADIM + lane]*at[lane];
      float vv  = bnatt[lane]*at[lane];
      #pragma unroll
      for (int o = 32; o > 0; o >>= 1){
        uu0 += __shfl_down(uu0, o, 64);
        uu1 += __shfl_down(uu1, o, 64);
        vv  += __shfl_down(vv,  o, 64);
      }
      if (lane == 0){
        bc[4] = uu0; bc[5] = uu1;
        bc[6] = pos0*uu0 + pos1*uu1 + vv;
      }
    }
    __syncthreads();
    u0 = bc[4]; u1 = bc[5]; A = bc[6];
  }
}

extern "C" void kernel_launch(void* const* d_in, const int* in_sizes, int n_in,
                              void* d_out, int out_size, void* d_ws, size_t ws_size,
                              hipStream_t stream) {
  const float* img   = (const float*)d_in[0];
  const float* tpos  = (const float*)d_in[1];
  const float* trel  = (const float*)d_in[2];
  const float* npos  = (const float*)d_in[3];
  const float* nrel  = (const float*)d_in[4];
  const int*   nhist = (const int*)d_in[5];
  const int*   ths   = (const int*)d_in[6];
  const float* th0   = (const float*)d_in[7];
  const float* tc0   = (const float*)d_in[8];
  const float* Wtemb = (const float*)d_in[9];
  const float* btemb = (const float*)d_in[10];
  const float* Wiht  = (const float*)d_in[11];
  const float* Whht  = (const float*)d_in[12];
  const float* biht  = (const float*)d_in[13];
  const float* bhht  = (const float*)d_in[14];
  const float* Wtatt = (const float*)d_in[15];
  const float* btatt = (const float*)d_in[16];
  const float* nh0   = (const float*)d_in[17];
  const float* nc0   = (const float*)d_in[18];
  const float* Wnemb = (const float*)d_in[19];
  const float* bnemb = (const float*)d_in[20];
  const float* Wihn  = (const float*)d_in[21];
  const float* Whhn  = (const float*)d_in[22];
  const float* bihn  = (const float*)d_in[23];
  const float* bhhn  = (const float*)d_in[24];
  const float* Wnatt = (const float*)d_in[25];
  const float* bnatt = (const float*)d_in[26];
  const float* Wpred = (const float*)d_in[27];
  const float* bpred = (const float*)d_in[28];
  float* ws  = (float*)d_ws;
  float* out = (float*)d_out;

  k_prep<<<257, 256, 0, stream>>>(Whhn, Whht, Wnemb, bnemb, Wihn, bihn, bhhn,
                                  Wtemb, btemb, Wiht, biht, bhht, ws);
  k_phaseA<<<130, 256, 0, stream>>>(nh0, nc0, nrel, nhist, Wpred,
                                    trel, ths, Whht, th0, tc0,
                                    tpos, npos, Wtatt, btatt, Wnatt, bnatt, ws);
  k_phaseB<<<1, 512, 0, stream>>>(img, tpos, npos, nh0, Wpred, bpred,
                                  Wtatt, btatt, Wnatt, bnatt, ws, out);
}

// Round 5
// 890.276 us; speedup vs baseline: 4.1430x; 1.8860x over previous
//
#include <hip/hip_runtime.h>
#include <hip/hip_bf16.h>
#include <cstdint>

#define LH   50
#define PP   30
#define NAG  2048
#define NHID 128
#define EHID 256
#define ADIM 64
#define CNND 2048

typedef __attribute__((ext_vector_type(8))) short bf16x8;
typedef __attribute__((ext_vector_type(4))) float f32x4;

// ---- workspace layout (float slots) -----------------------------------------
enum : int {
  WS_WT  = 0,        // bf16 Wstage[c=8][j=1024][k'=32]  -> 131072 float slots (512 KB)
  WS_WHT = 131072,   // bf16 WhtT[512][128]       -> 32768
  WS_WFN = 163840,   // 2*1024 folded (W_nemb@Wih_n)
  WS_BFN = 165888,   // 1024
  WS_WFT = 166912,   // 2*512 folded (W_temb@Wih_t)
  WS_BFT = 167936,   // 512
  WS_TH  = 168448,   // 128  (th after obs chain)
  WS_TC  = 168576,   // 128
  WS_W49 = 168704,   // 2048 obs softmax weights
  WS_CN  = 170752,   // 1    currN(49)
  WS_Z   = 170756,   // 30*2048*2 = 122880
  WS_END = 293636
};

__device__ __forceinline__ float sigf(float x){ return 1.0f/(1.0f + __expf(-x)); }
__device__ __forceinline__ float tanhfast(float x){
  x = fminf(15.0f, fmaxf(-15.0f, x));
  float e = __expf(2.0f*x);
  return (e - 1.0f)/(e + 1.0f);
}
__device__ __forceinline__ float bfs(short s){
  return __uint_as_float(((unsigned)(unsigned short)s) << 16);
}
__device__ __forceinline__ void gld16(const void* g, void* l){
  __builtin_amdgcn_global_load_lds(
      (const __attribute__((address_space(1))) unsigned int*)g,
      (__attribute__((address_space(3))) unsigned int*)l, 16, 0, 0);
}

// ---- prep: Wstage (bf16, chunked), WhtT (bf16), folded gate weights ----------
// grid 257 x 256: blocks 0..255 transpose Whh_n; block 256 does folds + WhtT.
__global__ void k_prep(const float* __restrict__ Whhn, const float* __restrict__ Whht,
                       const float* __restrict__ Wnemb, const float* __restrict__ bnemb,
                       const float* __restrict__ Wihn,  const float* __restrict__ bihn,
                       const float* __restrict__ bhhn,
                       const float* __restrict__ Wtemb, const float* __restrict__ btemb,
                       const float* __restrict__ Wiht,  const float* __restrict__ biht,
                       const float* __restrict__ bhht,
                       float* __restrict__ ws)
{
  const int b = blockIdx.x, tid = threadIdx.x;
  if (b < 256){
    __shared__ float t[32][33];
    __hip_bfloat16* WT = (__hip_bfloat16*)(ws + WS_WT);
    const int tx = tid & 31, ty = tid >> 5;     // ty in [0,8)
    const int j0 = (b & 31) << 5;
    const int e0 = (b >> 5) << 5;
    #pragma unroll
    for (int r = 0; r < 4; ++r)
      t[ty + 8*r][tx] = Whhn[(e0 + ty + 8*r)*1024 + j0 + tx];
    __syncthreads();
    // Wstage[c][j][k'] with c = e0>>5, k' = tx, j = j0+ty+8r
    const int c = e0 >> 5;
    #pragma unroll
    for (int r = 0; r < 4; ++r)
      WT[c*32768 + (j0 + ty + 8*r)*32 + tx] = __float2bfloat16(t[tx][ty + 8*r]);
  } else {
    // nearby folds
    for (int j = tid; j < 1024; j += 256){
      float a0=0.f, a1=0.f, ab=0.f;
      for (int k=0;k<64;k++){
        const float w = Wihn[k*1024 + j];
        a0 += Wnemb[k]*w; a1 += Wnemb[64+k]*w; ab += bnemb[k]*w;
      }
      ws[WS_WFN + j]        = a0;
      ws[WS_WFN + 1024 + j] = a1;
      ws[WS_BFN + j]        = ab + bihn[j] + bhhn[j];
    }
    // target folds
    for (int j = tid; j < 512; j += 256){
      float a0=0.f, a1=0.f, ab=0.f;
      for (int k=0;k<64;k++){
        const float w = Wiht[k*512 + j];
        a0 += Wtemb[k]*w; a1 += Wtemb[64+k]*w; ab += btemb[k]*w;
      }
      ws[WS_WFT + j]       = a0;
      ws[WS_WFT + 512 + j] = a1;
      ws[WS_BFT + j]       = ab + biht[j] + bhht[j];
    }
    // WhtT bf16 [j=512][k=128]
    __hip_bfloat16* WTt = (__hip_bfloat16*)(ws + WS_WHT);
    for (int j = tid; j < 512; j += 256)
      for (int k = 0; k < 128; ++k)
        WTt[j*128 + k] = __float2bfloat16(Whht[k*512 + j]);
  }
}

// ---- Phase A: 78-step nearby chain (blocks 0..127, 512 thr, DMA-pipelined)
//      + target obs chain (block 128) + w49 precompute (block 129).
// Dynamic LDS layout (147968 B):
//   [0,131072)        short wbuf[2][32768]   double-buffered weight chunks
//   [131072,139520)   short Hl[16][264]
//   [139520,145920)   float relS[16][100]
//   [145920,147968)   float vS[256][2]
__global__ __launch_bounds__(512, 2) void k_phaseA(
    const float* __restrict__ nh0, const float* __restrict__ nc0,
    const float* __restrict__ nrel, const int* __restrict__ nhist,
    const float* __restrict__ Wpred,
    const float* __restrict__ trel, const int* __restrict__ thsp,
    const float* __restrict__ Whht, const float* __restrict__ th0,
    const float* __restrict__ tc0,
    const float* __restrict__ tpos, const float* __restrict__ npos,
    const float* __restrict__ Wtatt, const float* __restrict__ btatt,
    const float* __restrict__ Wnatt, const float* __restrict__ bnatt,
    float* __restrict__ ws)
{
  extern __shared__ char smem_raw[];
  const int b = blockIdx.x, tid = threadIdx.x;
  const int wv = tid >> 6, lane = tid & 63;
  const int lhi = lane >> 4, llo = lane & 15;

  if (b < 128){
    short* wbuf = (short*)smem_raw;
    short* Hl   = (short*)(smem_raw + 131072);
    float* relS = (float*)(smem_raw + 139520);
    float* vS   = (float*)(smem_raw + 145920);
    const int n0 = b << 4;

    for (int i = tid; i < 1600; i += 512){
      const int a = i / 100, r = i % 100;
      relS[a*100 + r] = nrel[(n0 + a)*100 + r];
    }
    if (tid < 256){
      vS[2*tid]   = Wpred[2*(NHID + CNND + tid)];
      vS[2*tid+1] = Wpred[2*(NHID + CNND + tid) + 1];
    }
    for (int i = tid; i < 4096; i += 512){
      const int a = i >> 8, e = i & 255;
      ((__hip_bfloat16*)Hl)[a*264 + e] = __float2bfloat16(nh0[e]);
    }

    // per-thread constants: gate j = g*256 + wv*32 + t*16 + llo
    float wf0[4][2], wf1[4][2], wb[4][2];
    #pragma unroll
    for (int g = 0; g < 4; ++g)
      #pragma unroll
      for (int t = 0; t < 2; ++t){
        const int j = g*256 + (wv<<5) + t*16 + llo;
        wf0[g][t] = ws[WS_WFN + j];
        wf1[g][t] = ws[WS_WFN + 1024 + j];
        wb [g][t] = ws[WS_BFN + j];
      }
    float C[4][2], ho[4][2];
    #pragma unroll
    for (int r = 0; r < 4; ++r)
      #pragma unroll
      for (int t = 0; t < 2; ++t){
        const int eo = (wv<<5) + t*16 + llo;
        C[r][t]  = nc0[eo];
        ho[r][t] = nh0[eo];
      }
    int nh4[4];
    #pragma unroll
    for (int r = 0; r < 4; ++r) nh4[r] = nhist[n0 + lhi*4 + r];

    const char* wgbase = (const char*)(ws + WS_WT);
    __syncthreads();

    // prologue: stage chunk 0 into buf0
    {
      const char* gsrc = wgbase + wv*8192 + lane*16;
      char* ldst = (char*)wbuf + wv*8192;
      #pragma unroll
      for (int i = 0; i < 8; ++i) gld16(gsrc + i*1024, ldst + i*1024);
    }
    __syncthreads();
    int cur = 0;

    for (int st = 1; st <= 78; ++st){
      const int thr  = (st <= 49) ? (50 - st) : -1;
      const int tsel = (st <= 49) ? st : 49;

      bf16x8 af[8];
      const short* hrow = Hl + llo*264 + lhi*8;
      #pragma unroll
      for (int c = 0; c < 8; ++c) af[c] = *(const bf16x8*)(hrow + c*32);

      f32x4 acc[4][2];
      #pragma unroll
      for (int g = 0; g < 4; ++g)
        #pragma unroll
        for (int t = 0; t < 2; ++t) acc[g][t] = (f32x4){0.f,0.f,0.f,0.f};

      #pragma unroll
      for (int c = 0; c < 8; ++c){
        // issue async stage of next chunk into the other buffer
        {
          const int nc = (c + 1) & 7;
          const char* gsrc = wgbase + nc*65536 + wv*8192 + lane*16;
          char* ldst = (char*)wbuf + (cur^1)*65536 + wv*8192;
          #pragma unroll
          for (int i = 0; i < 8; ++i) gld16(gsrc + i*1024, ldst + i*1024);
        }
        // consume current chunk
        const short* bbase = wbuf + cur*32768;
        #pragma unroll
        for (int g = 0; g < 4; ++g)
          #pragma unroll
          for (int t = 0; t < 2; ++t){
            const int j = g*256 + (wv<<5) + t*16 + llo;
            const bf16x8 bf = *(const bf16x8*)(bbase + j*32 + lhi*8);
            acc[g][t] = __builtin_amdgcn_mfma_f32_16x16x32_bf16(af[c], bf, acc[g][t], 0,0,0);
          }
        __syncthreads();   // drains vmcnt(0)+lgkmcnt(0): next chunk staged, buffer safe
        cur ^= 1;
      }

      #pragma unroll
      for (int r = 0; r < 4; ++r){
        const float r0 = relS[(lhi*4 + r)*100 + 2*tsel];
        const float r1 = relS[(lhi*4 + r)*100 + 2*tsel + 1];
        const bool mk = nh4[r] > thr;
        #pragma unroll
        for (int t = 0; t < 2; ++t){
          const float gi = acc[0][t][r] + r0*wf0[0][t] + r1*wf1[0][t] + wb[0][t];
          const float gf = acc[1][t][r] + r0*wf0[1][t] + r1*wf1[1][t] + wb[1][t];
          const float gg = acc[2][t][r] + r0*wf0[2][t] + r1*wf1[2][t] + wb[2][t];
          const float go = acc[3][t][r] + r0*wf0[3][t] + r1*wf1[3][t] + wb[3][t];
          const float c2 = sigf(gf)*C[r][t] + sigf(gi)*tanhfast(gg);
          const float h2 = sigf(go)*tanhfast(c2);
          if (mk){ C[r][t] = c2; ho[r][t] = h2; }
        }
      }
      #pragma unroll
      for (int r = 0; r < 4; ++r)
        #pragma unroll
        for (int t = 0; t < 2; ++t)
          ((__hip_bfloat16*)Hl)[(lhi*4 + r)*264 + (wv<<5) + t*16 + llo] =
              __float2bfloat16(ho[r][t]);
      __syncthreads();

      if (st >= 49){
        const int s = st - 49;
        const int a = wv*2 + (lane >> 5);
        const int sub = lane & 31;
        float z0 = 0.f, z1 = 0.f;
        const short* hp = Hl + a*264 + sub*8;
        #pragma unroll
        for (int i = 0; i < 8; ++i){
          const float h = bfs(hp[i]);
          z0 += h*vS[2*(sub*8 + i)];
          z1 += h*vS[2*(sub*8 + i) + 1];
        }
        #pragma unroll
        for (int o = 16; o > 0; o >>= 1){
          z0 += __shfl_down(z0, o, 32);
          z1 += __shfl_down(z1, o, 32);
        }
        if (sub == 0){
          ws[WS_Z + (s*NAG + n0 + a)*2]     = z0;
          ws[WS_Z + (s*NAG + n0 + a)*2 + 1] = z1;
        }
      }
    }
  }
  else if (b == 128){
    // ---- target obs chain (49 steps), 512 threads, 1 gate col each ----
    float* hT = (float*)smem_raw;
    float* cT = hT + 128;
    float* gT = cT + 128;   // 512
    if (tid < 128){ hT[tid] = th0[tid]; cT[tid] = tc0[tid]; }
    __syncthreads();
    const int ths = thsp[0];
    for (int t = 1; t < 50; ++t){
      const float x0 = trel[2*t], x1 = trel[2*t+1];
      float acc = x0*ws[WS_WFT + tid] + x1*ws[WS_WFT + 512 + tid] + ws[WS_BFT + tid];
      for (int k = 0; k < 128; ++k) acc += hT[k]*Whht[k*512 + tid];
      gT[tid] = acc;
      __syncthreads();
      if (tid < 128 && ths > 50 - t){
        const float ig = sigf(gT[tid]),          fg = sigf(gT[128 + tid]);
        const float gg = tanhfast(gT[256 + tid]), og = sigf(gT[384 + tid]);
        const float c2 = fg*cT[tid] + ig*gg;
        cT[tid] = c2; hT[tid] = og*tanhfast(c2);
      }
      __syncthreads();
    }
    if (tid < 128){ ws[WS_TH + tid] = hT[tid]; ws[WS_TC + tid] = cT[tid]; }
  }
  else {
    // ---- w49 precompute (obs-final attention weights), 512 threads ----
    float* at  = (float*)smem_raw;       // 64
    float* red = at + 64;                // 512
    float* uv  = red + 512;              // 3
    const int t = LH - 1;
    const float tr0 = trel[2*t], tr1 = trel[2*t+1];
    const float tp0 = tpos[2*t], tp1 = tpos[2*t+1];
    if (tid < ADIM) at[tid] = tr0*Wtatt[tid] + tr1*Wtatt[ADIM+tid] + btatt[tid];
    int cnt = 0;
    #pragma unroll
    for (int i = 0; i < 4; ++i) cnt += (nhist[tid + 512*i] > (LH - t)) ? 1 : 0;
    red[tid] = (float)cnt;
    __syncthreads();
    if (tid == 0){
      float u0=0.f,u1=0.f,v=0.f;
      for (int k=0;k<ADIM;k++){ u0 += Wnatt[k]*at[k]; u1 += Wnatt[ADIM+k]*at[k]; v += bnatt[k]*at[k]; }
      uv[0]=u0; uv[1]=u1; uv[2]=v;
    }
    for (int s = 256; s > 0; s >>= 1){ if (tid < s) red[tid] += red[tid+s]; __syncthreads(); }
    const float currN = red[0];
    __syncthreads();
    const float u0 = uv[0], u1 = uv[1], v = uv[2];
    const float scale = currN * 0.125f;
    float sc[4]; float smax = -3.0e38f;
    #pragma unroll
    for (int i = 0; i < 4; ++i){
      const int n = tid + 512*i;
      const float p0 = npos[n*100 + 2*t], p1 = npos[n*100 + 2*t + 1];
      float s = scale * ((tp0-p0)*u0 + (tp1-p1)*u1 + v);
      s = (nhist[n] > (LH - t)) ? s : -1.0e30f;
      sc[i] = s; smax = fmaxf(smax, s);
    }
    red[tid] = smax; __syncthreads();
    for (int s = 256; s > 0; s >>= 1){ if (tid<s) red[tid] = fmaxf(red[tid], red[tid+s]); __syncthreads(); }
    smax = red[0]; __syncthreads();
    float ssum = 0.f;
    #pragma unroll
    for (int i = 0; i < 4; ++i){ sc[i] = __expf(sc[i]-smax); ssum += sc[i]; }
    red[tid] = ssum; __syncthreads();
    for (int s = 256; s > 0; s >>= 1){ if (tid<s) red[tid] += red[tid+s]; __syncthreads(); }
    const float inv = 1.0f / red[0];
    #pragma unroll
    for (int i = 0; i < 4; ++i) ws[WS_W49 + tid + 512*i] = sc[i]*inv;
    if (tid == 0) ws[WS_CN] = currN;
  }
}

// ---- Phase B: all 30 pred steps in one block ---------------------------------
template<int K>
__device__ __forceinline__ void bredN(const float* v, volatile float* scratch,
                                      volatile float* outv, int tid){
  const int lane = tid & 63, wv = tid >> 6;
  #pragma unroll
  for (int k = 0; k < K; ++k){
    float x = v[k];
    #pragma unroll
    for (int o = 32; o > 0; o >>= 1) x += __shfl_down(x, o, 64);
    if (lane == 0) scratch[k*8 + wv] = x;
  }
  __syncthreads();
  if (tid == 0){
    #pragma unroll
    for (int k = 0; k < K; ++k){
      float s = 0.f;
      for (int i = 0; i < 8; ++i) s += scratch[k*8 + i];
      outv[k] = s;
    }
  }
  __syncthreads();
}

__device__ __forceinline__ float bredMax1(float x, volatile float* scratch,
                                          volatile float* outv, int tid){
  const int lane = tid & 63, wv = tid >> 6;
  #pragma unroll
  for (int o = 32; o > 0; o >>= 1) x = fmaxf(x, __shfl_down(x, o, 64));
  if (lane == 0) scratch[wv] = x;
  __syncthreads();
  if (tid == 0){
    float s = -3.0e38f;
    for (int i = 0; i < 8; ++i) s = fmaxf(s, scratch[i]);
    outv[0] = s;
  }
  __syncthreads();
  return outv[0];
}

__global__ __launch_bounds__(512, 1) void k_phaseB(
    const float* __restrict__ img, const float* __restrict__ tpos,
    const float* __restrict__ npos, const float* __restrict__ nh0,
    const float* __restrict__ Wpred, const float* __restrict__ bpred,
    const float* __restrict__ Wtatt, const float* __restrict__ btatt,
    const float* __restrict__ Wnatt, const float* __restrict__ bnatt,
    float* __restrict__ ws, float* __restrict__ out)
{
  __shared__ float p0s[NAG], p1s[NAG];
  __shared__ float th[128], tc[128], gl[512], at[64];
  __shared__ float scratch[24];
  __shared__ float bc[8];
  const int tid = threadIdx.x, lane = tid & 63, wv = tid >> 6;

  bf16x8 wreg[16];
  {
    const short* wp = (const short*)(ws + WS_WHT) + tid*128;
    #pragma unroll
    for (int f = 0; f < 16; ++f) wreg[f] = *(const bf16x8*)(wp + f*8);
  }
  for (int n = tid; n < NAG; n += 512){
    p0s[n] = npos[n*100 + 98];
    p1s[n] = npos[n*100 + 99];
  }
  if (tid < 128){ th[tid] = ws[WS_TH + tid]; tc[tid] = ws[WS_TC + tid]; }

  {
    float v[2] = {0.f, 0.f};
    for (int k = tid; k < CNND; k += 512){
      v[0] += img[k]*Wpred[2*(128 + k)];
      v[1] += img[k]*Wpred[2*(128 + k) + 1];
    }
    bredN<2>(v, scratch, bc, tid);
  }
  const float imgW0 = bc[0], imgW1 = bc[1];
  {
    float v[2] = {0.f, 0.f};
    if (tid < 256){
      v[0] = nh0[tid]*Wpred[2*(128 + CNND + tid)];
      v[1] = nh0[tid]*Wpred[2*(128 + CNND + tid) + 1];
    }
    bredN<2>(v, scratch, bc + 2, tid);
  }
  const float fb0 = bc[2], fb1 = bc[3];
  const float currN = ws[WS_CN];
  float pos0 = tpos[98], pos1 = tpos[99];
  float u0 = 0.f, u1 = 0.f, A = 0.f;
  __syncthreads();

  for (int s = 0; s < PP; ++s){
    const float* zs = ws + WS_Z + s*(NAG*2);
    float hv0, hv1;
    if (s == 0){
      if (currN >= 1.0f){
        float v[2] = {0.f, 0.f};
        for (int n = tid; n < NAG; n += 512){
          const float w = ws[WS_W49 + n];
          v[0] += w*zs[2*n]; v[1] += w*zs[2*n + 1];
        }
        bredN<2>(v, scratch, bc, tid);
        hv0 = bc[0]; hv1 = bc[1];
      } else { hv0 = fb0; hv1 = fb1; }
    } else {
      float sc[4], mx = -3.0e38f;
      #pragma unroll
      for (int i = 0; i < 4; ++i){
        const int n = tid + 512*i;
        sc[i] = 256.0f * (A - (p0s[n]*u0 + p1s[n]*u1));
        mx = fmaxf(mx, sc[i]);
      }
      mx = bredMax1(mx, scratch, bc + 7, tid);
      float v[3] = {0.f, 0.f, 0.f};
      #pragma unroll
      for (int i = 0; i < 4; ++i){
        const int n = tid + 512*i;
        const float e = __expf(sc[i] - mx);
        v[0] += e; v[1] += e*zs[2*n]; v[2] += e*zs[2*n + 1];
      }
      bredN<3>(v, scratch, bc, tid);
      const float inv = 1.0f / bc[0];
      hv0 = bc[1]*inv; hv1 = bc[2]*inv;
    }
    {
      float v[2] = {0.f, 0.f};
      if (tid < 128){
        v[0] = th[tid]*Wpred[2*tid];
        v[1] = th[tid]*Wpred[2*tid + 1];
      }
      bredN<2>(v, scratch, bc + 2, tid);
    }
    const float pr0 = bc[2] + imgW0 + hv0 + bpred[0];
    const float pr1 = bc[3] + imgW1 + hv1 + bpred[1];
    if (tid == 0){ out[2*s] = pr0; out[2*s + 1] = pr1; }
    pos0 += pr0; pos1 += pr1;

    {
      float g = pr0*ws[WS_WFT + tid] + pr1*ws[WS_WFT + 512 + tid] + ws[WS_BFT + tid];
      #pragma unroll
      for (int f = 0; f < 16; ++f){
        #pragma unroll
        for (int i = 0; i < 8; ++i)
          g += bfs(wreg[f][i]) * th[f*8 + i];
      }
      gl[tid] = g;
    }
    __syncthreads();
    float hnew = 0.f, cnew = 0.f;
    if (tid < 128){
      const float ig = sigf(gl[tid]),           fg = sigf(gl[128 + tid]);
      const float gg = tanhfast(gl[256 + tid]), og = sigf(gl[384 + tid]);
      cnew = fg*tc[tid] + ig*gg;
      hnew = og*tanhfast(cnew);
    }
    __syncthreads();
    if (tid < 128){ th[tid] = hnew; tc[tid] = cnew; }

    if (tid < ADIM) at[tid] = pr0*Wtatt[tid] + pr1*Wtatt[ADIM + tid] + btatt[tid];
    __syncthreads();
    if (wv == 0){
      float uu0 = Wnatt[lane]*at[lane];
      float uu1 = Wnatt[ADIM + lane]*at[lane];
      float vv  = bnatt[lane]*at[lane];
      #pragma unroll
      for (int o = 32; o > 0; o >>= 1){
        uu0 += __shfl_down(uu0, o, 64);
        uu1 += __shfl_down(uu1, o, 64);
        vv  += __shfl_down(vv,  o, 64);
      }
      if (lane == 0){
        bc[4] = uu0; bc[5] = uu1;
        bc[6] = pos0*uu0 + pos1*uu1 + vv;
      }
    }
    __syncthreads();
    u0 = bc[4]; u1 = bc[5]; A = bc[6];
  }
}

extern "C" void kernel_launch(void* const* d_in, const int* in_sizes, int n_in,
                              void* d_out, int out_size, void* d_ws, size_t ws_size,
                              hipStream_t stream) {
  const float* img   = (const float*)d_in[0];
  const float* tpos  = (const float*)d_in[1];
  const float* trel  = (const float*)d_in[2];
  const float* npos  = (const float*)d_in[3];
  const float* nrel  = (const float*)d_in[4];
  const int*   nhist = (const int*)d_in[5];
  const int*   ths   = (const int*)d_in[6];
  const float* th0   = (const float*)d_in[7];
  const float* tc0   = (const float*)d_in[8];
  const float* Wtemb = (const float*)d_in[9];
  const float* btemb = (const float*)d_in[10];
  const float* Wiht  = (const float*)d_in[11];
  const float* Whht  = (const float*)d_in[12];
  const float* biht  = (const float*)d_in[13];
  const float* bhht  = (const float*)d_in[14];
  const float* Wtatt = (const float*)d_in[15];
  const float* btatt = (const float*)d_in[16];
  const float* nh0   = (const float*)d_in[17];
  const float* nc0   = (const float*)d_in[18];
  const float* Wnemb = (const float*)d_in[19];
  const float* bnemb = (const float*)d_in[20];
  const float* Wihn  = (const float*)d_in[21];
  const float* Whhn  = (const float*)d_in[22];
  const float* bihn  = (const float*)d_in[23];
  const float* bhhn  = (const float*)d_in[24];
  const float* Wnatt = (const float*)d_in[25];
  const float* bnatt = (const float*)d_in[26];
  const float* Wpred = (const float*)d_in[27];
  const float* bpred = (const float*)d_in[28];
  float* ws  = (float*)d_ws;
  float* out = (float*)d_out;

  k_prep<<<257, 256, 0, stream>>>(Whhn, Whht, Wnemb, bnemb, Wihn, bihn, bhhn,
                                  Wtemb, btemb, Wiht, biht, bhht, ws);
  k_phaseA<<<130, 512, 147968, stream>>>(nh0, nc0, nrel, nhist, Wpred,
                                         trel, ths, Whht, th0, tc0,
                                         tpos, npos, Wtatt, btatt, Wnatt, bnatt, ws);
  k_phaseB<<<1, 512, 0, stream>>>(img, tpos, npos, nh0, Wpred, bpred,
                                  Wtatt, btatt, Wnatt, bnatt, ws, out);
}